// Round 8
// baseline (249.309 us; speedup 1.0000x reference)
//
#include <hip/hip_runtime.h>
#include <hip/hip_fp16.h>
#include <math.h>

typedef _Float16 f16x8 __attribute__((ext_vector_type(8)));
typedef _Float16 f16x4 __attribute__((ext_vector_type(4)));
typedef float    f32x4 __attribute__((ext_vector_type(4)));

#define M_TOT 32768   // 8*64*64 pixels

// ---------------------------------------------------------------------------
// async global->LDS, 16B per lane. LDS dest = wave-uniform base + lane*16.
// ---------------------------------------------------------------------------
__device__ __forceinline__ void gload16(const void* g, void* l) {
    __builtin_amdgcn_global_load_lds(
        (const __attribute__((address_space(1))) unsigned int*)g,
        (__attribute__((address_space(3))) unsigned int*)l, 16, 0, 0);
}

// ---------------------------------------------------------------------------
// x (fp32) -> fp16
// ---------------------------------------------------------------------------
__global__ __launch_bounds__(256) void conv_x(const float* __restrict__ x,
                                              __half* __restrict__ y) {
    const size_t i = ((size_t)blockIdx.x * 256 + threadIdx.x) * 8;
    float4 a = *(const float4*)&x[i];
    float4 b = *(const float4*)&x[i + 4];
    __half2 h[4];
    h[0] = __floats2half2_rn(a.x, a.y);
    h[1] = __floats2half2_rn(a.z, a.w);
    h[2] = __floats2half2_rn(b.x, b.y);
    h[3] = __floats2half2_rn(b.z, b.w);
    *(float4*)&y[i] = *(float4*)h;
}

// ---------------------------------------------------------------------------
// weights -> fp16, transposed to [n][k]; q-scale 0.125 folded into wq.
// ---------------------------------------------------------------------------
__global__ __launch_bounds__(256) void conv_w(const float* __restrict__ wq,
                                              const float* __restrict__ wkv,
                                              const float* __restrict__ wout,
                                              __half* __restrict__ wT,
                                              __half* __restrict__ woT) {
    const int id = blockIdx.x * 256 + threadIdx.x;   // < 2048*512
    const int nr = id >> 9, k = id & 511;
    if (nr < 512) {
        wT[(size_t)nr * 512 + k]  = __float2half(wq[k * 512 + nr] * 0.125f);
    } else if (nr < 1536) {
        wT[(size_t)nr * 512 + k]  = __float2half(wkv[k * 1024 + (nr - 512)]);
    } else {
        woT[(size_t)(nr - 1536) * 512 + k] = __float2half(wout[k * 512 + (nr - 1536)]);
    }
}

// ---------------------------------------------------------------------------
// fp16 MFMA GEMM (m97 structure), BM=BN=128, BK=32, 4 waves.
// MODE 0: proj epilogue -> q16, k16, and vT (value part pre-transposed).
// MODE 1: fp32 store to outf.
// ---------------------------------------------------------------------------
template <int MODE>
__global__ __launch_bounds__(256) void mfma_gemm(
    const __half* __restrict__ A, const __half* __restrict__ Bt,
    __half* __restrict__ q16, __half* __restrict__ k16, __half* __restrict__ vT,
    float* __restrict__ outf)
{
    __shared__ _Float16 As[128 * 32];
    __shared__ _Float16 Bs[128 * 32];

    const int t = threadIdx.x;
    const int l = t & 63, w = t >> 6;
    const int wr = w >> 1, wc = w & 1;
    const int bm = blockIdx.x, bn = blockIdx.y;

    f32x4 zero = {0.f, 0.f, 0.f, 0.f};
    f32x4 acc[4][4];
    #pragma unroll
    for (int i = 0; i < 4; ++i)
        #pragma unroll
        for (int j = 0; j < 4; ++j) acc[i][j] = zero;

    const int srow = w * 32 + (l >> 2);
    const int sch  = (l & 3) * 8;
    const size_t abase = (size_t)(bm * 128 + srow) * 512 + sch;
    const size_t bbase = (size_t)(bn * 128 + srow) * 512 + sch;
    _Float16* ldsA0 = &As[(w * 2 + 0) * 512];
    _Float16* ldsA1 = &As[(w * 2 + 1) * 512];
    _Float16* ldsB0 = &Bs[(w * 2 + 0) * 512];
    _Float16* ldsB1 = &Bs[(w * 2 + 1) * 512];

    const int lr = l & 15, lk = (l >> 4) * 8;

    for (int k0 = 0; k0 < 512; k0 += 32) {
        gload16(A  + abase + k0,            ldsA0);
        gload16(A  + abase + 16 * 512 + k0, ldsA1);
        gload16(Bt + bbase + k0,            ldsB0);
        gload16(Bt + bbase + 16 * 512 + k0, ldsB1);
        __syncthreads();

        f16x8 af[4], bf[4];
        #pragma unroll
        for (int i = 0; i < 4; ++i)
            af[i] = *(const f16x8*)&As[(wr * 64 + i * 16 + lr) * 32 + lk];
        #pragma unroll
        for (int j = 0; j < 4; ++j)
            bf[j] = *(const f16x8*)&Bs[(wc * 64 + j * 16 + lr) * 32 + lk];
        #pragma unroll
        for (int i = 0; i < 4; ++i)
            #pragma unroll
            for (int j = 0; j < 4; ++j)
                acc[i][j] = __builtin_amdgcn_mfma_f32_16x16x32_f16(af[i], bf[j], acc[i][j], 0, 0, 0);
        __syncthreads();
    }

    const int lq = l >> 4;
    #pragma unroll
    for (int i = 0; i < 4; ++i) {
        #pragma unroll
        for (int j = 0; j < 4; ++j) {
            const int row0 = bm * 128 + wr * 64 + i * 16 + lq * 4;
            const int col  = bn * 128 + wc * 64 + j * 16 + lr;
            if (MODE == 1) {
                #pragma unroll
                for (int r = 0; r < 4; ++r)
                    outf[(size_t)(row0 + r) * 512 + col] = acc[i][j][r];
            } else if (bn < 4) {
                #pragma unroll
                for (int r = 0; r < 4; ++r)
                    q16[(size_t)(row0 + r) * 512 + col] = __float2half(acc[i][j][r]);
            } else if (wc == 0) {           // key part
                const int head = bn - 4, d2 = j * 16 + lr;
                #pragma unroll
                for (int r = 0; r < 4; ++r)
                    k16[(size_t)(row0 + r) * 512 + head * 64 + d2] = __float2half(acc[i][j][r]);
            } else {                        // value part -> vT[(b*8+head)*64+d][pix]
                const int head = bn - 4, d2 = j * 16 + lr;
                const int bb = row0 >> 12, pix = row0 & 4095;  // 4 consecutive pixels
                f16x4 pv;
                #pragma unroll
                for (int r = 0; r < 4; ++r) pv[r] = (_Float16)acc[i][j][r];
                *(f16x4*)(vT + ((size_t)((bb * 8 + head) * 64 + d2)) * 4096 + pix) = pv;
            }
        }
    }
}

// ---------------------------------------------------------------------------
// MFMA halo attention, 8 waves (512 thr): wave (g = w&3, h = w>>2) owns
// key quarter g x query half h for QK^T/softmax, and dim quarter g x
// query half h for PV. LDS 52.7 KB -> 3 blocks/CU -> 24 waves/CU.
// ---------------------------------------------------------------------------
__global__ __launch_bounds__(512, 3) void halo_attn(
    const __half* __restrict__ qbuf, const __half* __restrict__ kbuf,
    const __half* __restrict__ vT,
    const float* __restrict__ posw, const float* __restrict__ posh,
    const __half* __restrict__ zp,
    __half* __restrict__ obuf)
{
    __shared__ __align__(16) char KP[64 * 520];   // 33280 B: posA-tiles -> K(swz) -> P
    __shared__ float RWT[32][68];                 // rel_w^T [idx][q] f32
    __shared__ float RHT[32][68];                 // rel_h^T [idx][q] f32
    __shared__ float red[4][64];
    __shared__ float red2[4][64];

    // XCD swizzle: contiguous 512-block chunk (one batch) per XCD
    const int hw = blockIdx.x;
    const int wg = (hw & 7) * 512 + (hw >> 3);
    const int wb = wg & 7, hb = (wg >> 3) & 7, n = (wg >> 6) & 7, b = wg >> 9;
    const int t = threadIdx.x;
    const int l = t & 63, w = t >> 6;
    const int g = w & 3, h = w >> 2;
    const int hi = l >> 4, c15 = l & 15;

    // ---- V B-frags direct from vT: lane (c15,hi) -> dim g*16+c15,
    //      keys kc*16 + hi*4 + j (contiguous in x) ----
    f16x4 vfrag[16];
    {
        const __half* vrow = vT + ((size_t)((b * 8 + n) * 64 + g * 16 + c15)) * 4096;
        const int x0 = wb * 8 - 4 + hi * 4;
        const bool okx = (unsigned)x0 < 64u;
        #pragma unroll
        for (int kc = 0; kc < 16; ++kc) {
            const int y = hb * 8 - 4 + kc;
            const bool ok = okx && ((unsigned)y < 64u);
            const __half* p = ok ? (vrow + y * 64 + x0) : zp;
            vfrag[kc] = *(const f16x4*)p;
        }
    }

    // ---- stage pos tables as swizzled MFMA A-tiles: KP + tb*4096,
    //      entry (idx,d) at byte (idx*128 + d*2) ^ ((idx&7)<<4); row 31 = 0 ----
    for (int j5 = t; j5 < 4096; j5 += 512) {
        const int tb = j5 >> 11, idx = (j5 >> 6) & 31, d = j5 & 63;
        const float* src = tb ? posh : posw;
        const float v = (idx < 31) ? src[d * 31 + idx] : 0.f;
        *(__half*)(KP + tb * 4096 + ((idx * 128 + d * 2) ^ ((idx & 7) << 4))) = __float2half(v);
    }

    // ---- Q fragments (B-operand of 16x16x32): qreg[j][dc], qf = h*2+j ----
    f16x8 qreg[2][2];
    #pragma unroll
    for (int j = 0; j < 2; ++j) {
        const int q = (h * 2 + j) * 16 + c15;
        const size_t pix = (size_t)((b * 64 + hb * 8 + (q >> 3)) * 64 + wb * 8 + (q & 7));
        #pragma unroll
        for (int dc = 0; dc < 2; ++dc)
            qreg[j][dc] = *(const f16x8*)(qbuf + pix * 512 + n * 64 + dc * 32 + hi * 8);
    }
    __syncthreads();   // B0: pos A-tiles staged

    // ---- pos MFMA: wave (g,h) -> table tb=g>>1, idx-half ih=g&1, 2 q-frags ----
    f32x4 accp[2];
    accp[0] = (f32x4){0.f, 0.f, 0.f, 0.f};
    accp[1] = accp[0];
    {
        const int tb = g >> 1, ih = g & 1;
        const char* base = KP + tb * 4096;
        const int row = ih * 16 + c15;
        #pragma unroll
        for (int dc = 0; dc < 2; ++dc) {
            const int off = (row * 128 + dc * 64 + hi * 16) ^ ((row & 7) << 4);
            f16x8 a = *(const f16x8*)(base + off);
            #pragma unroll
            for (int j = 0; j < 2; ++j)
                accp[j] = __builtin_amdgcn_mfma_f32_16x16x32_f16(a, qreg[j][dc], accp[j], 0, 0, 0);
        }
    }
    __syncthreads();   // B1: pos-table reads done -> KP free for K

    // ---- issue K staging via global_load_lds (source pre-swizzled) ----
    #pragma unroll
    for (int it = 0; it < 4; ++it) {
        const int cid = it * 512 + t;
        const int S = cid * 16;                       // linear LDS byte
        const int row = S >> 7;                       // key 0..255
        const int d0h = (((S & 127) >> 4) ^ (row & 7)) * 8;   // halves
        const int ky = hb * 8 - 4 + (row >> 4);
        const int kx = wb * 8 - 4 + (row & 15);
        const bool ok = ((unsigned)ky < 64u) && ((unsigned)kx < 64u);
        const __half* src = ok ? (kbuf + ((size_t)((b * 64 + ky) * 64 + kx)) * 512 + n * 64 + d0h)
                               : zp;
        gload16(src, KP + (it * 512 + w * 64) * 16);
    }

    // ---- write pos D-frags to RWT/RHT f32 (overlaps with K loads in flight) ----
    {
        const int tb = g >> 1, ih = g & 1;
        float (*dst)[68] = tb ? RHT : RWT;
        #pragma unroll
        for (int j = 0; j < 2; ++j)
            #pragma unroll
            for (int r = 0; r < 4; ++r)
                dst[ih * 16 + hi * 4 + r][(h * 2 + j) * 16 + c15] = accp[j][r];
    }
    __syncthreads();   // B2: K landed, RWT/RHT visible

    // ---- QK^T: S^T frags, A=K (swizzled LDS, quarter g), B=Q regs (half h) ----
    f32x4 accs[4][2];
    #pragma unroll
    for (int kf = 0; kf < 4; ++kf)
        #pragma unroll
        for (int j = 0; j < 2; ++j) accs[kf][j] = (f32x4){0.f, 0.f, 0.f, 0.f};

    #pragma unroll
    for (int kf = 0; kf < 4; ++kf) {
        const int row = g * 64 + kf * 16 + c15;
        #pragma unroll
        for (int dc = 0; dc < 2; ++dc) {
            const int off = (row * 128 + dc * 64 + hi * 16) ^ ((row & 7) << 4);
            f16x8 a = *(const f16x8*)(KP + off);
            #pragma unroll
            for (int j = 0; j < 2; ++j)
                accs[kf][j] = __builtin_amdgcn_mfma_f32_16x16x32_f16(a, qreg[j][dc], accs[kf][j], 0, 0, 0);
        }
    }

    // ---- bias + per-quarter max (lane keys: g*64 + kf*16 + hi*4 + r) ----
    float mq[2];
    #pragma unroll
    for (int j = 0; j < 2; ++j) {
        const int q = (h * 2 + j) * 16 + c15;
        const int qj = q & 7, qi = q >> 3;
        float pa[4], pb[4];
        #pragma unroll
        for (int r = 0; r < 4; ++r)  pa[r] = RWT[hi * 4 + r - qj + 15][q];
        #pragma unroll
        for (int kf = 0; kf < 4; ++kf) pb[kf] = RHT[g * 4 + kf - qi + 15][q];
        float mm = -1e30f;
        #pragma unroll
        for (int kf = 0; kf < 4; ++kf)
            #pragma unroll
            for (int r = 0; r < 4; ++r) {
                const float s = accs[kf][j][r] + pa[r] + pb[kf];
                accs[kf][j][r] = s;
                mm = fmaxf(mm, s);
            }
        mm = fmaxf(mm, __shfl_xor(mm, 16));
        mm = fmaxf(mm, __shfl_xor(mm, 32));
        mq[j] = mm;
    }
    if (l < 16) {
        #pragma unroll
        for (int j = 0; j < 2; ++j) red[g][(h * 2 + j) * 16 + l] = mq[j];
    }
    __syncthreads();   // B3: maxes visible; K reads done -> KP becomes P

    // ---- exp + sums + pack P into LDS [q] pitch 520B fp16 ----
    float sums[2];
    #pragma unroll
    for (int j = 0; j < 2; ++j) {
        const int q = (h * 2 + j) * 16 + c15;
        const float mfull = fmaxf(fmaxf(red[0][q], red[1][q]), fmaxf(red[2][q], red[3][q]));
        float ss = 0.f;
        #pragma unroll
        for (int kf = 0; kf < 4; ++kf)
            #pragma unroll
            for (int r = 0; r < 4; ++r) {
                const float p = __expf(accs[kf][j][r] - mfull);
                accs[kf][j][r] = p;
                ss += p;
            }
        ss += __shfl_xor(ss, 16);
        ss += __shfl_xor(ss, 32);
        sums[j] = ss;
        #pragma unroll
        for (int kf = 0; kf < 4; ++kf) {
            __half2 h01 = __floats2half2_rn(accs[kf][j][0], accs[kf][j][1]);
            __half2 h23 = __floats2half2_rn(accs[kf][j][2], accs[kf][j][3]);
            uint2 wv;
            wv.x = *(unsigned*)&h01;
            wv.y = *(unsigned*)&h23;
            *(uint2*)(KP + q * 520 + (g * 64 + kf * 16 + hi * 4) * 2) = wv;
        }
    }
    if (l < 16) {
        #pragma unroll
        for (int j = 0; j < 2; ++j) red2[g][(h * 2 + j) * 16 + l] = sums[j];
    }
    __syncthreads();   // B4: P + sums visible

    // ---- PV via 16x16x16: wave (g,h) -> dims [g*16,+16), queries half h ----
    f32x4 acco[2];
    acco[0] = (f32x4){0.f, 0.f, 0.f, 0.f};
    acco[1] = acco[0];
    #pragma unroll
    for (int kc = 0; kc < 16; ++kc) {
        const f16x4 bf = vfrag[kc];
        #pragma unroll
        for (int j = 0; j < 2; ++j) {
            const f16x4 af = *(const f16x4*)(KP + ((h * 2 + j) * 16 + c15) * 520 + (kc * 16 + hi * 4) * 2);
            acco[j] = __builtin_amdgcn_mfma_f32_16x16x16f16(af, bf, acco[j], 0, 0, 0);
        }
    }

    // ---- normalize + store (D: col=dim=c15, rows q=hi*4+r within frag) ----
    #pragma unroll
    for (int j = 0; j < 2; ++j) {
        #pragma unroll
        for (int r = 0; r < 4; ++r) {
            const int q = (h * 2 + j) * 16 + hi * 4 + r;
            const float den = red2[0][q] + red2[1][q] + red2[2][q] + red2[3][q];
            const float v = acco[j][r] / den;
            const size_t pix = (size_t)((b * 64 + hb * 8 + (q >> 3)) * 64 + wb * 8 + (q & 7));
            obuf[pix * 512 + n * 64 + g * 16 + c15] = __float2half(v);
        }
    }
}

// ---------------------------------------------------------------------------
extern "C" void kernel_launch(void* const* d_in, const int* in_sizes, int n_in,
                              void* d_out, int out_size, void* d_ws, size_t ws_size,
                              hipStream_t stream)
{
    const float* x    = (const float*)d_in[0];
    const float* wq   = (const float*)d_in[1];
    const float* wkv  = (const float*)d_in[2];
    const float* wout = (const float*)d_in[3];
    const float* posw = (const float*)d_in[4];
    const float* posh = (const float*)d_in[5];
    float* out = (float*)d_out;

    // fp16 workspace (162 MB): vT written directly by proj epilogue.
    const size_t NPIX = (size_t)M_TOT * 512;
    __half* x16 = (__half*)d_ws;            // 32 MB
    __half* wT  = x16 + NPIX;               // 1.5 MB
    __half* woT = wT + (size_t)1536 * 512;  // 0.5 MB
    __half* q16 = woT + (size_t)512 * 512;  // 32 MB
    __half* k16 = q16 + NPIX;               // 32 MB
    __half* vT  = k16 + NPIX;               // 32 MB  [(b*8+n)*64+d][4096 px]
    __half* o16 = vT + NPIX;                // 32 MB
    __half* zp  = o16 + NPIX;               // 256 B zero page

    hipMemsetAsync(zp, 0, 256, stream);

    conv_x<<<(M_TOT * 512) / (256 * 8), 256, 0, stream>>>(x, x16);
    conv_w<<<(2048 * 512) / 256, 256, 0, stream>>>(wq, wkv, wout, wT, woT);

    dim3 g1(M_TOT / 128, 12);
    mfma_gemm<0><<<g1, 256, 0, stream>>>(x16, wT, q16, k16, vT, nullptr);

    halo_attn<<<4096, 512, 0, stream>>>(q16, k16, vT, posw, posh, zp, o16);

    dim3 g3(M_TOT / 128, 4);
    mfma_gemm<1><<<g3, 256, 0, stream>>>(o16, woT, nullptr, nullptr, nullptr, out);
}

// Round 9
// 227.960 us; speedup vs baseline: 1.0937x; 1.0937x over previous
//
#include <hip/hip_runtime.h>
#include <hip/hip_fp16.h>
#include <math.h>

typedef _Float16 f16x8 __attribute__((ext_vector_type(8)));
typedef _Float16 f16x4 __attribute__((ext_vector_type(4)));
typedef float    f32x4 __attribute__((ext_vector_type(4)));

#define M_TOT 32768   // 8*64*64 pixels
#define VROW  4608    // padded vT row: 64 y * 72 x

// ---------------------------------------------------------------------------
// async global->LDS, 16B per lane. LDS dest = wave-uniform base + lane*16.
// ---------------------------------------------------------------------------
__device__ __forceinline__ void gload16(const void* g, void* l) {
    __builtin_amdgcn_global_load_lds(
        (const __attribute__((address_space(1))) unsigned int*)g,
        (__attribute__((address_space(3))) unsigned int*)l, 16, 0, 0);
}

// ---------------------------------------------------------------------------
// x (fp32) -> fp16
// ---------------------------------------------------------------------------
__global__ __launch_bounds__(256) void conv_x(const float* __restrict__ x,
                                              __half* __restrict__ y) {
    const size_t i = ((size_t)blockIdx.x * 256 + threadIdx.x) * 8;
    float4 a = *(const float4*)&x[i];
    float4 b = *(const float4*)&x[i + 4];
    __half2 h[4];
    h[0] = __floats2half2_rn(a.x, a.y);
    h[1] = __floats2half2_rn(a.z, a.w);
    h[2] = __floats2half2_rn(b.x, b.y);
    h[3] = __floats2half2_rn(b.z, b.w);
    *(float4*)&y[i] = *(float4*)h;
}

// ---------------------------------------------------------------------------
// weights -> fp16, transposed to [n][k]; q-scale 0.125 folded into wq.
// ---------------------------------------------------------------------------
__global__ __launch_bounds__(256) void conv_w(const float* __restrict__ wq,
                                              const float* __restrict__ wkv,
                                              const float* __restrict__ wout,
                                              __half* __restrict__ wT,
                                              __half* __restrict__ woT) {
    const int id = blockIdx.x * 256 + threadIdx.x;   // < 2048*512
    const int nr = id >> 9, k = id & 511;
    if (nr < 512) {
        wT[(size_t)nr * 512 + k]  = __float2half(wq[k * 512 + nr] * 0.125f);
    } else if (nr < 1536) {
        wT[(size_t)nr * 512 + k]  = __float2half(wkv[k * 1024 + (nr - 512)]);
    } else {
        woT[(size_t)(nr - 1536) * 512 + k] = __float2half(wout[k * 512 + (nr - 1536)]);
    }
}

// ---------------------------------------------------------------------------
// zero the 4-px x-borders of padded vT (8 halves per (row,y))
// ---------------------------------------------------------------------------
__global__ __launch_bounds__(256) void vborder(__half* __restrict__ vTp) {
    const int id = blockIdx.x * 256 + threadIdx.x;   // < 4096*64*2
    const int row = id >> 7, rem = id & 127;
    const int y = rem >> 1, side = rem & 1;
    f16x4 z = {(_Float16)0.f, (_Float16)0.f, (_Float16)0.f, (_Float16)0.f};
    *(f16x4*)(vTp + (size_t)row * VROW + y * 72 + side * 68) = z;
}

// ---------------------------------------------------------------------------
// fp16 MFMA GEMM (m97 structure), BM=BN=128, BK=32, 4 waves.
// MODE 0: proj epilogue -> q16, k16, and vTp (value part, padded transpose).
// MODE 1: fp32 store to outf.
// ---------------------------------------------------------------------------
template <int MODE>
__global__ __launch_bounds__(256) void mfma_gemm(
    const __half* __restrict__ A, const __half* __restrict__ Bt,
    __half* __restrict__ q16, __half* __restrict__ k16, __half* __restrict__ vTp,
    float* __restrict__ outf)
{
    __shared__ _Float16 As[128 * 32];
    __shared__ _Float16 Bs[128 * 32];

    const int t = threadIdx.x;
    const int l = t & 63, w = t >> 6;
    const int wr = w >> 1, wc = w & 1;
    const int bm = blockIdx.x, bn = blockIdx.y;

    f32x4 zero = {0.f, 0.f, 0.f, 0.f};
    f32x4 acc[4][4];
    #pragma unroll
    for (int i = 0; i < 4; ++i)
        #pragma unroll
        for (int j = 0; j < 4; ++j) acc[i][j] = zero;

    const int srow = w * 32 + (l >> 2);
    const int sch  = (l & 3) * 8;
    const size_t abase = (size_t)(bm * 128 + srow) * 512 + sch;
    const size_t bbase = (size_t)(bn * 128 + srow) * 512 + sch;
    _Float16* ldsA0 = &As[(w * 2 + 0) * 512];
    _Float16* ldsA1 = &As[(w * 2 + 1) * 512];
    _Float16* ldsB0 = &Bs[(w * 2 + 0) * 512];
    _Float16* ldsB1 = &Bs[(w * 2 + 1) * 512];

    const int lr = l & 15, lk = (l >> 4) * 8;

    for (int k0 = 0; k0 < 512; k0 += 32) {
        gload16(A  + abase + k0,            ldsA0);
        gload16(A  + abase + 16 * 512 + k0, ldsA1);
        gload16(Bt + bbase + k0,            ldsB0);
        gload16(Bt + bbase + 16 * 512 + k0, ldsB1);
        __syncthreads();

        f16x8 af[4], bf[4];
        #pragma unroll
        for (int i = 0; i < 4; ++i)
            af[i] = *(const f16x8*)&As[(wr * 64 + i * 16 + lr) * 32 + lk];
        #pragma unroll
        for (int j = 0; j < 4; ++j)
            bf[j] = *(const f16x8*)&Bs[(wc * 64 + j * 16 + lr) * 32 + lk];
        #pragma unroll
        for (int i = 0; i < 4; ++i)
            #pragma unroll
            for (int j = 0; j < 4; ++j)
                acc[i][j] = __builtin_amdgcn_mfma_f32_16x16x32_f16(af[i], bf[j], acc[i][j], 0, 0, 0);
        __syncthreads();
    }

    const int lq = l >> 4;
    #pragma unroll
    for (int i = 0; i < 4; ++i) {
        #pragma unroll
        for (int j = 0; j < 4; ++j) {
            const int row0 = bm * 128 + wr * 64 + i * 16 + lq * 4;
            const int col  = bn * 128 + wc * 64 + j * 16 + lr;
            if (MODE == 1) {
                #pragma unroll
                for (int r = 0; r < 4; ++r)
                    outf[(size_t)(row0 + r) * 512 + col] = acc[i][j][r];
            } else if (bn < 4) {
                #pragma unroll
                for (int r = 0; r < 4; ++r)
                    q16[(size_t)(row0 + r) * 512 + col] = __float2half(acc[i][j][r]);
            } else if (wc == 0) {           // key part
                const int head = bn - 4, d2 = j * 16 + lr;
                #pragma unroll
                for (int r = 0; r < 4; ++r)
                    k16[(size_t)(row0 + r) * 512 + head * 64 + d2] = __float2half(acc[i][j][r]);
            } else {                        // value part -> vTp[(b*8+head)*64+d][y*72+x+4]
                const int head = bn - 4, d2 = j * 16 + lr;
                const int bb = row0 >> 12, pix = row0 & 4095;  // 4 consecutive x, same y
                const int py = pix >> 6, px = pix & 63;
                f16x4 pv;
                #pragma unroll
                for (int r = 0; r < 4; ++r) pv[r] = (_Float16)acc[i][j][r];
                *(f16x4*)(vTp + ((size_t)((bb * 8 + head) * 64 + d2)) * VROW + py * 72 + px + 4) = pv;
            }
        }
    }
}

// ---------------------------------------------------------------------------
// MFMA halo attention, 4 waves (256 thr): wave g owns key quarter
// [g*64,+64) for QK^T/softmax and dim quarter [g*16,+16) for PV (K=32).
// K staged FIRST (latency overlap); pos tiles live in the RWT/RHT region.
// LDS 53248 B -> 3 blocks/CU.
// ---------------------------------------------------------------------------
__global__ __launch_bounds__(256, 3) void halo_attn(
    const __half* __restrict__ qbuf, const __half* __restrict__ kbuf,
    const __half* __restrict__ vTp,
    const float* __restrict__ posw, const float* __restrict__ posh,
    const __half* __restrict__ zp,
    __half* __restrict__ obuf)
{
    __shared__ __align__(16) char KP[64 * 528];   // 33792 B: K(swz) -> P (pitch 528)
    __shared__ __align__(16) char PTRW[17408];    // pos A-tiles -> RWT/RHT f32
    __shared__ float red[4][64];
    __shared__ float red2[4][64];

    float (*RWT)[68] = (float(*)[68])PTRW;                // [32][68] f32
    float (*RHT)[68] = (float(*)[68])(PTRW + 8704);

    // XCD swizzle: contiguous 512-block chunk (one batch) per XCD
    const int hw = blockIdx.x;
    const int wg = (hw & 7) * 512 + (hw >> 3);
    const int wb = wg & 7, hb = (wg >> 3) & 7, n = (wg >> 6) & 7, b = wg >> 9;
    const int t = threadIdx.x;
    const int l = t & 63, g = t >> 6;
    const int hi = l >> 4, c15 = l & 15;

    // ---- 1) issue K staging FIRST (global_load_lds, source pre-swizzled) ----
    #pragma unroll
    for (int it = 0; it < 8; ++it) {
        const int cid = it * 256 + t;
        const int S = cid * 16;                       // linear LDS byte
        const int row = S >> 7;                       // key 0..255
        const int d0h = (((S & 127) >> 4) ^ (row & 7)) * 8;   // halves
        const int ky = hb * 8 - 4 + (row >> 4);
        const int kx = wb * 8 - 4 + (row & 15);
        const bool ok = ((unsigned)ky < 64u) && ((unsigned)kx < 64u);
        const __half* src = ok ? (kbuf + ((size_t)((b * 64 + ky) * 64 + kx)) * 512 + n * 64 + d0h)
                               : zp;
        gload16(src, KP + (it * 256 + g * 64) * 16);
    }

    // ---- 2) V B-frags (16x16x32): lane (c15,hi) -> dim g*16+c15,
    //         keys kc*32 + hi*8 + j -> contiguous 16B in padded vT ----
    f16x8 vfrag[8];
    {
        const __half* vrow = vTp + ((size_t)((b * 8 + n) * 64 + g * 16 + c15)) * VROW;
        const int xoff = wb * 8 + (hi & 1) * 8;       // (wb*8-4 + kj0) + 4
        #pragma unroll
        for (int kc = 0; kc < 8; ++kc) {
            const int ki = kc * 2 + (hi >> 1);
            const int y = hb * 8 - 4 + ki;
            const __half* p = ((unsigned)y < 64u) ? (vrow + y * 72 + xoff) : zp;
            vfrag[kc] = *(const f16x8*)p;
        }
    }

    // ---- 3) stage pos tables as swizzled MFMA A-tiles into PTRW ----
    for (int j5 = t; j5 < 4096; j5 += 256) {
        const int tb = j5 >> 11, idx = (j5 >> 6) & 31, d = j5 & 63;
        const float* src = tb ? posh : posw;
        const float v = (idx < 31) ? src[d * 31 + idx] : 0.f;
        *(__half*)(PTRW + tb * 4096 + ((idx * 128 + d * 2) ^ ((idx & 7) << 4))) = __float2half(v);
    }

    // ---- 4) Q fragments (B-operand of 16x16x32): qreg[qf][dc] ----
    f16x8 qreg[4][2];
    #pragma unroll
    for (int qf = 0; qf < 4; ++qf) {
        const int q = qf * 16 + c15;
        const size_t pix = (size_t)((b * 64 + hb * 8 + (q >> 3)) * 64 + wb * 8 + (q & 7));
        #pragma unroll
        for (int dc = 0; dc < 2; ++dc)
            qreg[qf][dc] = *(const f16x8*)(qbuf + pix * 512 + n * 64 + dc * 32 + hi * 8);
    }
    __syncthreads();   // B0: pos tiles staged (K drained here too)

    // ---- pos MFMA: wave g -> table tb=g>>1, idx-half ih=g&1 (8 MFMA) ----
    f32x4 accp[4];
    #pragma unroll
    for (int qf = 0; qf < 4; ++qf) accp[qf] = (f32x4){0.f, 0.f, 0.f, 0.f};
    {
        const int tb = g >> 1, ih = g & 1;
        const char* base = PTRW + tb * 4096;
        const int row = ih * 16 + c15;
        #pragma unroll
        for (int dc = 0; dc < 2; ++dc) {
            const int off = (row * 128 + dc * 64 + hi * 16) ^ ((row & 7) << 4);
            f16x8 a = *(const f16x8*)(base + off);
            #pragma unroll
            for (int qf = 0; qf < 4; ++qf)
                accp[qf] = __builtin_amdgcn_mfma_f32_16x16x32_f16(a, qreg[qf][dc], accp[qf], 0, 0, 0);
        }
    }
    __syncthreads();   // B1: pos-tile reads done -> PTRW reusable as RWT/RHT

    // ---- write pos D-frags to RWT/RHT f32 ----
    {
        const int tb = g >> 1, ih = g & 1;
        float (*dst)[68] = tb ? RHT : RWT;
        #pragma unroll
        for (int qf = 0; qf < 4; ++qf)
            #pragma unroll
            for (int r = 0; r < 4; ++r)
                dst[ih * 16 + hi * 4 + r][qf * 16 + c15] = accp[qf][r];
    }
    __syncthreads();   // B2: RWT/RHT visible; K already landed

    // ---- QK^T: S^T frags, A=K (swizzled LDS, quarter g), B=Q regs ----
    f32x4 accs[4][4];
    #pragma unroll
    for (int kf = 0; kf < 4; ++kf)
        #pragma unroll
        for (int qf = 0; qf < 4; ++qf) accs[kf][qf] = (f32x4){0.f, 0.f, 0.f, 0.f};

    #pragma unroll
    for (int kf = 0; kf < 4; ++kf) {
        const int row = g * 64 + kf * 16 + c15;
        #pragma unroll
        for (int dc = 0; dc < 2; ++dc) {
            const int off = (row * 128 + dc * 64 + hi * 16) ^ ((row & 7) << 4);
            f16x8 a = *(const f16x8*)(KP + off);
            #pragma unroll
            for (int qf = 0; qf < 4; ++qf)
                accs[kf][qf] = __builtin_amdgcn_mfma_f32_16x16x32_f16(a, qreg[qf][dc], accs[kf][qf], 0, 0, 0);
        }
    }

    // ---- bias + per-quarter max (lane keys: g*64 + kf*16 + hi*4 + r) ----
    float mq[4];
    #pragma unroll
    for (int qf = 0; qf < 4; ++qf) {
        const int q = qf * 16 + c15;
        const int qj = q & 7, qi = q >> 3;
        float pa[4], pb[4];
        #pragma unroll
        for (int r = 0; r < 4; ++r)  pa[r] = RWT[hi * 4 + r - qj + 15][q];
        #pragma unroll
        for (int kf = 0; kf < 4; ++kf) pb[kf] = RHT[g * 4 + kf - qi + 15][q];
        float mm = -1e30f;
        #pragma unroll
        for (int kf = 0; kf < 4; ++kf)
            #pragma unroll
            for (int r = 0; r < 4; ++r) {
                const float s = accs[kf][qf][r] + pa[r] + pb[kf];
                accs[kf][qf][r] = s;
                mm = fmaxf(mm, s);
            }
        mm = fmaxf(mm, __shfl_xor(mm, 16));
        mm = fmaxf(mm, __shfl_xor(mm, 32));
        mq[qf] = mm;
    }
    if (l < 16) {
        #pragma unroll
        for (int qf = 0; qf < 4; ++qf) red[g][qf * 16 + l] = mq[qf];
    }
    __syncthreads();   // B3: maxes visible; K reads done -> KP becomes P

    // ---- exp + sums + pack P into LDS [q] pitch 528B fp16 ----
    float sums[4];
    #pragma unroll
    for (int qf = 0; qf < 4; ++qf) {
        const int q = qf * 16 + c15;
        const float mfull = fmaxf(fmaxf(red[0][q], red[1][q]), fmaxf(red[2][q], red[3][q]));
        float ss = 0.f;
        #pragma unroll
        for (int kf = 0; kf < 4; ++kf)
            #pragma unroll
            for (int r = 0; r < 4; ++r) {
                const float p = __expf(accs[kf][qf][r] - mfull);
                accs[kf][qf][r] = p;
                ss += p;
            }
        ss += __shfl_xor(ss, 16);
        ss += __shfl_xor(ss, 32);
        sums[qf] = ss;
        #pragma unroll
        for (int kf = 0; kf < 4; ++kf) {
            __half2 h01 = __floats2half2_rn(accs[kf][qf][0], accs[kf][qf][1]);
            __half2 h23 = __floats2half2_rn(accs[kf][qf][2], accs[kf][qf][3]);
            uint2 wv;
            wv.x = *(unsigned*)&h01;
            wv.y = *(unsigned*)&h23;
            *(uint2*)(KP + q * 528 + (g * 64 + kf * 16 + hi * 4) * 2) = wv;
        }
    }
    if (l < 16) {
        #pragma unroll
        for (int qf = 0; qf < 4; ++qf) red2[g][qf * 16 + l] = sums[qf];
    }
    __syncthreads();   // B4: P + sums visible

    // ---- PV via 16x16x32: wave g owns dims [g*16,+16), 8 kc steps ----
    f32x4 acco[4];
    #pragma unroll
    for (int qf = 0; qf < 4; ++qf) acco[qf] = (f32x4){0.f, 0.f, 0.f, 0.f};
    #pragma unroll
    for (int kc = 0; kc < 8; ++kc) {
        const f16x8 bf = vfrag[kc];
        #pragma unroll
        for (int qf = 0; qf < 4; ++qf) {
            const f16x8 af = *(const f16x8*)(KP + (qf * 16 + c15) * 528 + kc * 64 + hi * 16);
            acco[qf] = __builtin_amdgcn_mfma_f32_16x16x32_f16(af, bf, acco[qf], 0, 0, 0);
        }
    }

    // ---- normalize + store (D: col=dim=c15, rows q=hi*4+r within frag) ----
    #pragma unroll
    for (int qf = 0; qf < 4; ++qf) {
        #pragma unroll
        for (int r = 0; r < 4; ++r) {
            const int q = qf * 16 + hi * 4 + r;
            const float den = red2[0][q] + red2[1][q] + red2[2][q] + red2[3][q];
            const float v = acco[qf][r] / den;
            const size_t pix = (size_t)((b * 64 + hb * 8 + (q >> 3)) * 64 + wb * 8 + (q & 7));
            obuf[pix * 512 + n * 64 + g * 16 + c15] = __float2half(v);
        }
    }
}

// ---------------------------------------------------------------------------
extern "C" void kernel_launch(void* const* d_in, const int* in_sizes, int n_in,
                              void* d_out, int out_size, void* d_ws, size_t ws_size,
                              hipStream_t stream)
{
    const float* x    = (const float*)d_in[0];
    const float* wq   = (const float*)d_in[1];
    const float* wkv  = (const float*)d_in[2];
    const float* wout = (const float*)d_in[3];
    const float* posw = (const float*)d_in[4];
    const float* posh = (const float*)d_in[5];
    float* out = (float*)d_out;

    // fp16 workspace (~174 MB): vTp = padded V transpose (x-pad 4 each side).
    const size_t NPIX = (size_t)M_TOT * 512;
    const size_t NVTP = (size_t)64 * 64 * VROW;    // 18.87M halves
    __half* x16 = (__half*)d_ws;            // 33.5 MB
    __half* wT  = x16 + NPIX;               // 1.5 MB
    __half* woT = wT + (size_t)1536 * 512;  // 0.5 MB
    __half* q16 = woT + (size_t)512 * 512;  // 33.5 MB
    __half* k16 = q16 + NPIX;               // 33.5 MB
    __half* vTp = k16 + NPIX;               // 37.7 MB
    __half* o16 = vTp + NVTP;               // 33.5 MB
    __half* zp  = o16 + NPIX;               // 256 B zero page

    hipMemsetAsync(zp, 0, 256, stream);

    conv_x<<<(M_TOT * 512) / (256 * 8), 256, 0, stream>>>(x, x16);
    conv_w<<<(2048 * 512) / 256, 256, 0, stream>>>(wq, wkv, wout, wT, woT);
    vborder<<<2048, 256, 0, stream>>>(vTp);

    dim3 g1(M_TOT / 128, 12);
    mfma_gemm<0><<<g1, 256, 0, stream>>>(x16, wT, q16, k16, vTp, nullptr);

    halo_attn<<<4096, 256, 0, stream>>>(q16, k16, vTp, posw, posh, zp, o16);

    dim3 g3(M_TOT / 128, 4);
    mfma_gemm<1><<<g3, 256, 0, stream>>>(o16, woT, nullptr, nullptr, nullptr, out);
}